// Round 7
// baseline (257.348 us; speedup 1.0000x reference)
//
#include <hip/hip_runtime.h>
#include <math.h>

#define S_LEN 1024
#define NHEAD 8
#define BATCH 8
#define KDIM  64
#define HID   32
#define NT    2048
#define TRI(q) ((q) * ((q) + 1) / 2)
// key-order bit-shuffle: m=[nb1 nb0 q1 q0 r1 r0] -> key=[nb1 q1 q0 nb0 r1 r0]
#define PERM(m) (((m) & 0x20) | (((m) & 0x0C) << 1) | (((m) & 0x10) >> 2) | ((m) & 3))
// LDS column swizzle key per row (3 bits, conflict-free for K(perm) and V reads)
#define SWZ(row) (((((row) >> 3) & 1) << 2) | ((row) & 3))

typedef __attribute__((ext_vector_type(8))) short bf16x8;
typedef __attribute__((ext_vector_type(4))) float f32x4;
typedef unsigned short ushort_t;

__device__ inline ushort_t f2bf(float f) {
  union { float f; unsigned u; } v; v.f = f;
  unsigned u = v.u;
  return (ushort_t)((u + 0x7FFFu + ((u >> 16) & 1u)) >> 16);
}
__device__ inline float bf2f(ushort_t u) {
  union { unsigned x; float f; } v; v.x = ((unsigned)u) << 16; return v.f;
}

// ---------------------------------------------------------------------------
// Kernel 1: prep = to_bf16 (blocks 0..5119) + fire_tables (blocks 5120..7175).
// ---------------------------------------------------------------------------
__global__ __launch_bounds__(256) void prep(
    const float* __restrict__ s, const float* __restrict__ wq,
    const float* __restrict__ wk, const float* __restrict__ wv,
    const float* __restrict__ wo,
    ushort_t* __restrict__ sb, ushort_t* __restrict__ wqb,
    ushort_t* __restrict__ wkb, ushort_t* __restrict__ wvb,
    ushort_t* __restrict__ wob,
    const float* __restrict__ c_raw, const float* __restrict__ Lp,
    const float* __restrict__ w1, const float* __restrict__ b1,
    const float* __restrict__ W2, const float* __restrict__ b2,
    const float* __restrict__ w3, const float* __restrict__ b3,
    float* __restrict__ num_g, float* __restrict__ rden_g,
    float* __restrict__ gtab_g) {
  __shared__ float h1s[8][33];
  const int bx = blockIdx.x;
  const int tid = threadIdx.x;
  if (bx < 5120) {
    const float* src; ushort_t* dst; int base; float scale = 1.0f;
    if (bx < 4096)      { src = s;  dst = sb;  base = bx; }
    else if (bx < 4352) { src = wq; dst = wqb; base = bx - 4096; scale = 0.125f; }
    else if (bx < 4608) { src = wk; dst = wkb; base = bx - 4352; }
    else if (bx < 4864) { src = wv; dst = wvb; base = bx - 4608; }
    else                { src = wo; dst = wob; base = bx - 4864; }
    const int i = (base * 256 + tid) * 4;
    float4 v = *(const float4*)&src[i];
    ushort4 o;
    o.x = f2bf(v.x * scale); o.y = f2bf(v.y * scale);
    o.z = f2bf(v.z * scale); o.w = f2bf(v.w * scale);
    *(ushort4*)&dst[i] = o;
  } else {
    const int idx = bx - 5120;
    const int h = idx / 257;
    const int xb = idx % 257;
    const float cr = c_raw[h];
    const float c = (cr > 20.f) ? cr : log1pf(expf(cr));
    const int gid = xb * 256 + tid;
    if (gid < S_LEN) {
      num_g[h * S_LEN + gid] = log1pf(c * (float)gid);
      rden_g[h * S_LEN + gid] = 1.0f / log1pf(c * fmaxf(Lp[h], (float)(gid + 1)));
    }
    const int pl = tid >> 5;             // point-local 0..7
    const int j = tid & 31;              // hidden dim
    const int pt = xb * 8 + pl;
    const float x = (float)pt * (1.0f / NT);
    float v = x * w1[h * HID + j] + b1[h * HID + j];
    h1s[pl][j] = 0.5f * v * (1.0f + erff(v * 0.70710678118f));
    __syncthreads();
    float sm = b2[h * HID + j];
    const float* w2r = W2 + ((size_t)(h * HID + j)) * HID;
    #pragma unroll
    for (int k = 0; k < HID; ++k) sm += w2r[k] * h1s[pl][k];
    float g = 0.5f * sm * (1.0f + erff(sm * 0.70710678118f));
    float y = w3[h * HID + j] * g;
    #pragma unroll
    for (int off = 1; off < 32; off <<= 1) y += __shfl_xor(y, off);
    if (j == 0 && pt <= NT) gtab_g[h * (NT + 1) + pt] = y + b3[h];
  }
}

// ---------------------------------------------------------------------------
// GEMM tile body: C = A(Mx512 bf16) * W^T (512x512 bf16, NxK). 128x128 tile,
// 2x2 wave grid (64x64/wave), BK=64. Register-prefetch pipelined staging:
// global loads for tile k+1 stay in flight across tile k's MFMA phase; the
// barrier never drains vmcnt (no global_load_lds). LDS layout: element
// (row, chunk c) at row*64 + (c ^ (row&7))*8 (XOR swizzle, 2-way max).
// mode 0: f32 row-major Mx512. mode 1: bf16 scatter [b,h,s,kd].
// mode 2: V^T bf16 [b,h,kd,s] via LDS transpose.
// ---------------------------------------------------------------------------
__device__ __forceinline__ void gemm_tile(
    ushort_t* sAB, const ushort_t* __restrict__ A, const ushort_t* __restrict__ Wp,
    void* __restrict__ outp, int mode, int m0, int n0, int tid) {
  ushort_t* sA = sAB;
  ushort_t* sB = sAB + 8192;
  const int lane = tid & 63, w = tid >> 6, quad = lane >> 4, l16 = lane & 15;
  const int wr = w >> 1, wc = w & 1;
  f32x4 acc[4][4];
  #pragma unroll
  for (int ia = 0; ia < 4; ++ia)
    #pragma unroll
    for (int ib = 0; ib < 4; ++ib) acc[ia][ib] = (f32x4)0.0f;

  const int sw = l16 & 7;

  // staging: thread -> (row = tid>>1, half = tid&1), 4 chunks of 8 ushorts
  const int row = tid >> 1, half = tid & 1, r7 = row & 7;
  const ushort_t* ag = &A[(size_t)(m0 + row) * 512 + half * 32];
  const ushort_t* bg = &Wp[(size_t)(n0 + row) * 512 + half * 32];
  uint4 pa[4], pb[4];
  #pragma unroll
  for (int i = 0; i < 4; ++i) {
    pa[i] = *(const uint4*)(ag + i * 8);
    pb[i] = *(const uint4*)(bg + i * 8);
  }

  for (int kt8 = 0; kt8 < 8; ++kt8) {
    __syncthreads();                       // LDS consumers of prev tile done
    #pragma unroll
    for (int i = 0; i < 4; ++i) {
      const int c = half * 4 + i;
      *(uint4*)&sA[row * 64 + ((c ^ r7) * 8)] = pa[i];
      *(uint4*)&sB[row * 64 + ((c ^ r7) * 8)] = pb[i];
    }
    __syncthreads();                       // LDS ready
    if (kt8 < 7) {
      #pragma unroll
      for (int i = 0; i < 4; ++i) {        // in flight through the MFMA phase
        pa[i] = *(const uint4*)(ag + (kt8 + 1) * 64 + i * 8);
        pb[i] = *(const uint4*)(bg + (kt8 + 1) * 64 + i * 8);
      }
    }
    #pragma unroll
    for (int ks = 0; ks < 2; ++ks) {
      const int off = ((ks * 4 + quad) ^ sw) * 8;
      bf16x8 af[4], bfr[4];
      #pragma unroll
      for (int i = 0; i < 4; ++i) {
        af[i] = *(bf16x8*)&sA[(wr * 64 + i * 16 + l16) * 64 + off];
        bfr[i] = *(bf16x8*)&sB[(wc * 64 + i * 16 + l16) * 64 + off];
      }
      #pragma unroll
      for (int ia = 0; ia < 4; ++ia)
        #pragma unroll
        for (int ib = 0; ib < 4; ++ib)
          acc[ia][ib] = __builtin_amdgcn_mfma_f32_16x16x32_bf16(af[ia], bfr[ib], acc[ia][ib], 0, 0, 0);
    }
  }

  if (mode == 2) {
    __syncthreads();
    #pragma unroll
    for (int ia = 0; ia < 4; ++ia)
      #pragma unroll
      for (int ib = 0; ib < 4; ++ib)
        #pragma unroll
        for (int r = 0; r < 4; ++r) {
          int nl = wc * 64 + ib * 16 + l16;
          int ml = wr * 64 + ia * 16 + quad * 4 + r;
          sAB[nl * 128 + (((ml >> 3) ^ (nl & 7)) * 8) + (ml & 7)] = f2bf(acc[ia][ib][r]);
        }
    __syncthreads();
    const int nl = tid >> 1, halfm = tid & 1;
    const int ng = n0 + nl, hh = ng >> 6, kd = ng & 63;
    const int bb = m0 >> 10, sbase = m0 & 1023;
    ushort_t* vout = (ushort_t*)outp + (((size_t)(bb * NHEAD + hh)) * KDIM + kd) * S_LEN;
    #pragma unroll
    for (int c2 = 0; c2 < 8; ++c2) {
      int mc = halfm * 8 + c2;
      bf16x8 vr = *(bf16x8*)&sAB[nl * 128 + ((mc ^ (nl & 7)) * 8)];
      *(bf16x8*)&vout[sbase + mc * 8] = vr;
    }
    return;
  }
  #pragma unroll
  for (int ia = 0; ia < 4; ++ia) {
    #pragma unroll
    for (int ib = 0; ib < 4; ++ib) {
      #pragma unroll
      for (int r = 0; r < 4; ++r) {
        int m = m0 + wr * 64 + ia * 16 + quad * 4 + r;
        int n = n0 + wc * 64 + ib * 16 + l16;
        float v = acc[ia][ib][r];
        if (mode == 1) {
          int bb = m >> 10, ss = m & 1023, hh = n >> 6, kd = n & 63;
          ((ushort_t*)outp)[(((size_t)(bb * NHEAD + hh)) * S_LEN + ss) * KDIM + kd] = f2bf(v);
        } else {
          ((float*)outp)[(size_t)m * 512 + n] = v;
        }
      }
    }
  }
}

// ---------------------------------------------------------------------------
// Kernel 2/4: gemm_bias. Blocks < nGemm: GEMM. Blocks >= nGemm: bias-pre
// (2 tiles per 256-thr block), fragment order for the transposed attention
// with PERM key order and causal -inf baked in.
// ---------------------------------------------------------------------------
__global__ __launch_bounds__(256) void gemm_bias(
    const ushort_t* __restrict__ A,
    const ushort_t* __restrict__ W0, const ushort_t* __restrict__ W1,
    const ushort_t* __restrict__ W2w,
    void* __restrict__ out0, void* __restrict__ out1, void* __restrict__ out2,
    int scatter, int nGemm,
    const float* __restrict__ num_g, const float* __restrict__ rden_g,
    const float* __restrict__ gtab_g, ushort_t* __restrict__ biaspre) {
  __shared__ __align__(16) ushort_t sAB[16384];
  const int tid = threadIdx.x;
  if ((int)blockIdx.x < nGemm) {
    const int z = blockIdx.x >> 8;
    const int idx = blockIdx.x & 255;
    const int m0 = (idx & 63) * 128;
    const int n0 = (idx >> 6) * 128;
    const ushort_t* Wp = (z == 0) ? W0 : (z == 1) ? W1 : W2w;
    void* outp = (z == 0) ? out0 : (z == 1) ? out1 : out2;
    const int mode = scatter ? ((z == 2) ? 2 : 1) : 0;
    gemm_tile(sAB, A, Wp, outp, mode, m0, n0, tid);
  } else {
    const int idx = blockIdx.x - nGemm;      // 0..543
    const int h = idx / 68;
    const int pair = idx % 68;
    float* gtab_s = (float*)sAB;             // 2049
    float* num_s = gtab_s + 2052;            // 1024
    float* rden_s = num_s + 1024;            // [2][64]
    for (int i = tid; i <= NT; i += 256) gtab_s[i] = gtab_g[h * (NT + 1) + i];
    for (int i = tid; i < S_LEN; i += 256) num_s[i] = num_g[h * S_LEN + i];
    const int sub = tid >> 7, tid2 = tid & 127;
    const int tileIdx = pair * 2 + sub;
    int qt = 0;
    while (TRI(qt + 1) <= tileIdx) ++qt;
    const int t = tileIdx - TRI(qt);
    if (tid2 < 64) rden_s[sub * 64 + tid2] = rden_g[h * S_LEN + qt * 64 + tid2];
    __syncthreads();
    const int w = tid2 >> 6, lane = tid2 & 63, quad = lane >> 4, l16 = lane & 15;
    ushort_t vals[32];
    #pragma unroll
    for (int qg = 0; qg < 2; ++qg) {
      const int iloc = w * 32 + qg * 16 + l16;
      const int i = qt * 64 + iloc;
      const float rden = rden_s[sub * 64 + iloc];
      #pragma unroll
      for (int nb = 0; nb < 4; ++nb)
        #pragma unroll
        for (int r = 0; r < 4; ++r) {
          const int m = nb * 16 + quad * 4 + r;
          const int j = t * 64 + PERM(m);
          ushort_t out;
          if (j > i) {
            out = 0xFF80;  // bf16 -inf (causal)
          } else {
            const int d = i - j;
            float x = num_s[d] * rden;       // in [0,1)
            float tf = x * (float)NT;
            int it = (int)tf; it = it < (NT - 1) ? it : (NT - 1);
            float fr = tf - (float)it;
            float ga = gtab_s[it];
            out = f2bf(ga + (gtab_s[it + 1] - ga) * fr);
          }
          vals[qg * 16 + nb * 4 + r] = out;
        }
    }
    ushort_t* dst = &biaspre[((size_t)(h * 136 + tileIdx) * 128 + tid2) * 32];
    uint4 u[2];
    #pragma unroll
    for (int half = 0; half < 2; ++half) {
      #pragma unroll
      for (int v = 0; v < 8; ++v) ((ushort_t*)&u[0])[v] = vals[half * 16 + v];
      #pragma unroll
      for (int v = 0; v < 8; ++v) ((ushort_t*)&u[1])[v] = vals[half * 16 + 8 + v];
      *(uint4*)(dst + half * 16) = u[0];
      *(uint4*)(dst + half * 16 + 8) = u[1];
    }
  }
}

// ---------------------------------------------------------------------------
// Kernel 3: transposed MFMA causal flash attention. 1024 blocks x 128 thr
// (2 waves x 32 q-rows), one (qt, b, h) each. S^T = K.Q^T with PERM'd key
// order; P^T fragments for O^T = V^T.P^T are register-local. K/V staged via
// register-prefetch pipeline (loads for t+1 in flight across tile t compute).
// ---------------------------------------------------------------------------
__global__ __launch_bounds__(128) void fire_attn_mfma(
    const ushort_t* __restrict__ Qg, const ushort_t* __restrict__ Kg,
    const ushort_t* __restrict__ Vtg, const ushort_t* __restrict__ biaspre,
    ushort_t* __restrict__ Ob) {
  __shared__ __align__(16) ushort_t Ks[64 * 64];
  __shared__ __align__(16) ushort_t Vt[64 * 64];
  const int tid = threadIdx.x;
  const int lane = tid & 63, w = tid >> 6, quad = lane >> 4, l16 = lane & 15;
  const int g = blockIdx.x >> 6;
  const int qt = (g < 8) ? (15 - g) : (g - 8);
  const int bh = blockIdx.x & 63, h = bh & 7, b = bh >> 3;

  // Q fragments (B-operand layout == A layout: [l16][quad*8+j]); Q pre-scaled 1/8
  bf16x8 q[2][2];
  {
    const size_t qb = (size_t)bh * S_LEN + qt * 64 + w * 32;
    #pragma unroll
    for (int qg = 0; qg < 2; ++qg)
      #pragma unroll
      for (int ks = 0; ks < 2; ++ks)
        q[qg][ks] = *(const bf16x8*)&Qg[(qb + qg * 16 + l16) * KDIM + ks * 32 + quad * 8];
  }

  const size_t kb = (size_t)bh * S_LEN * KDIM;
  const ushort_t* bptr = &biaspre[((size_t)(h * 136 + TRI(qt)) * 128 + tid) * 32];

  // staging: thread -> (row = tid>>1 in 0..63, half = tid&1), 4 chunks
  const int srow = tid >> 1, shalf = tid & 1;
  const int sswz = SWZ(srow);
  const ushort_t* kg = &Kg[kb + (size_t)srow * 64 + shalf * 32];     // + t*4096
  const ushort_t* vg = &Vtg[kb + (size_t)srow * 1024 + shalf * 32];  // + t*64
  uint4 pk[4], pv[4];
  #pragma unroll
  for (int i = 0; i < 4; ++i) {
    pk[i] = *(const uint4*)(kg + i * 8);
    pv[i] = *(const uint4*)(vg + i * 8);
  }

  f32x4 o[2][4];
  float ll[2] = {0.f, 0.f};
  #pragma unroll
  for (int qg = 0; qg < 2; ++qg)
    #pragma unroll
    for (int nb = 0; nb < 4; ++nb) o[qg][nb] = (f32x4)0.0f;

  for (int t = 0; t <= qt; ++t) {
    __syncthreads();
    #pragma unroll
    for (int i = 0; i < 4; ++i) {
      const int c = shalf * 4 + i;
      *(uint4*)&Ks[srow * 64 + ((c ^ sswz) * 8)] = pk[i];
      *(uint4*)&Vt[srow * 64 + ((c ^ sswz) * 8)] = pv[i];
    }
    __syncthreads();
    if (t < qt) {
      #pragma unroll
      for (int i = 0; i < 4; ++i) {        // in flight through this tile's MFMAs
        pk[i] = *(const uint4*)(kg + (size_t)(t + 1) * 4096 + i * 8);
        pv[i] = *(const uint4*)(vg + (size_t)(t + 1) * 64 + i * 8);
      }
    }

    // bias (fragment order, -inf baked)
    uint4 bb0 = ((const uint4*)(bptr + (size_t)t * 4096))[0];
    uint4 bb1 = ((const uint4*)(bptr + (size_t)t * 4096))[1];
    uint4 bb2 = ((const uint4*)(bptr + (size_t)t * 4096))[2];
    uint4 bb3 = ((const uint4*)(bptr + (size_t)t * 4096))[3];

    // ---- S^T = K . Q^T  (keys in PERM order on the m-dim)
    f32x4 s[2][4];
    #pragma unroll
    for (int qg = 0; qg < 2; ++qg)
      #pragma unroll
      for (int nb = 0; nb < 4; ++nb) s[qg][nb] = (f32x4)0.0f;
    #pragma unroll
    for (int ks = 0; ks < 2; ++ks) {
      #pragma unroll
      for (int nb = 0; nb < 4; ++nb) {
        const int rk = PERM(nb * 16 + l16);
        bf16x8 ak = *(bf16x8*)&Ks[rk * 64 + (((ks * 4 + quad) ^ SWZ(rk)) * 8)];
        #pragma unroll
        for (int qg = 0; qg < 2; ++qg)
          s[qg][nb] = __builtin_amdgcn_mfma_f32_16x16x32_bf16(ak, q[qg][ks], s[qg][nb], 0, 0, 0);
      }
    }

    // ---- P = exp(S + bias); no-max softmax (|logit| small); l per-lane
    ushort_t eb[2][16];
    #pragma unroll
    for (int qg = 0; qg < 2; ++qg) {
      #pragma unroll
      for (int nb = 0; nb < 4; ++nb)
        #pragma unroll
        for (int r = 0; r < 4; ++r) {
          const int v = qg * 16 + nb * 4 + r;
          const uint4& bq = (v < 8) ? bb0 : (v < 16) ? bb1 : (v < 24) ? bb2 : bb3;
          ushort_t bu = ((const ushort_t*)&bq)[v & 7];
          float p = __expf(s[qg][nb][r] + bf2f(bu));
          ll[qg] += p;
          eb[qg][nb * 4 + r] = f2bf(p);
        }
    }

    // ---- O^T += V^T . P^T   (P^T B-frags are register-local thanks to PERM)
    #pragma unroll
    for (int ks = 0; ks < 2; ++ks) {
      bf16x8 pf[2];
      #pragma unroll
      for (int qg = 0; qg < 2; ++qg) {
        union { bf16x8 v; unsigned u[4]; } pkx;
        pkx.u[0] = (unsigned)eb[qg][(2 * ks) * 4 + 0] | ((unsigned)eb[qg][(2 * ks) * 4 + 1] << 16);
        pkx.u[1] = (unsigned)eb[qg][(2 * ks) * 4 + 2] | ((unsigned)eb[qg][(2 * ks) * 4 + 3] << 16);
        pkx.u[2] = (unsigned)eb[qg][(2 * ks + 1) * 4 + 0] | ((unsigned)eb[qg][(2 * ks + 1) * 4 + 1] << 16);
        pkx.u[3] = (unsigned)eb[qg][(2 * ks + 1) * 4 + 2] | ((unsigned)eb[qg][(2 * ks + 1) * 4 + 3] << 16);
        pf[qg] = pkx.v;
      }
      #pragma unroll
      for (int nb = 0; nb < 4; ++nb) {
        const int rv = nb * 16 + l16;
        bf16x8 av = *(bf16x8*)&Vt[rv * 64 + (((ks * 4 + quad) ^ SWZ(rv)) * 8)];
        #pragma unroll
        for (int qg = 0; qg < 2; ++qg)
          o[qg][nb] = __builtin_amdgcn_mfma_f32_16x16x32_bf16(av, pf[qg], o[qg][nb], 0, 0, 0);
      }
    }
  }

  // ---- epilogue: l reduced across quads (qrow = qg*16+l16 for all lane vals)
  #pragma unroll
  for (int qg = 0; qg < 2; ++qg) {
    float rs = ll[qg];
    rs += __shfl_xor(rs, 16);
    rs += __shfl_xor(rs, 32);
    const float rl = 1.0f / rs;
    const size_t ob = ((size_t)(b * S_LEN + qt * 64 + w * 32 + qg * 16 + l16)) * 512 + h * KDIM;
    #pragma unroll
    for (int nb = 0; nb < 4; ++nb) {
      ushort4 ov;
      ov.x = f2bf(o[qg][nb][0] * rl);
      ov.y = f2bf(o[qg][nb][1] * rl);
      ov.z = f2bf(o[qg][nb][2] * rl);
      ov.w = f2bf(o[qg][nb][3] * rl);
      *(ushort4*)&Ob[ob + nb * 16 + quad * 4] = ov;
    }
  }
}

// ---------------------------------------------------------------------------
extern "C" void kernel_launch(void* const* d_in, const int* in_sizes, int n_in,
                              void* d_out, int out_size, void* d_ws, size_t ws_size,
                              hipStream_t stream) {
  const float* src   = (const float*)d_in[0];
  const float* Wq    = (const float*)d_in[1];
  const float* Wk    = (const float*)d_in[2];
  const float* Wv    = (const float*)d_in[3];
  const float* c_raw = (const float*)d_in[4];
  const float* Lp    = (const float*)d_in[5];
  const float* w1    = (const float*)d_in[6];
  const float* b1    = (const float*)d_in[7];
  const float* W2    = (const float*)d_in[8];
  const float* b2    = (const float*)d_in[9];
  const float* w3    = (const float*)d_in[10];
  const float* b3    = (const float*)d_in[11];
  const float* Wo    = (const float*)d_in[12];
  float* outp = (float*)d_out;

  const size_t SRC_E = 4194304;   // 8*1024*512
  const size_t W_E   = 262144;    // 512*512
  const size_t QKV_E = 4194304;   // 64*1024*64
  ushort_t* srcb = (ushort_t*)d_ws;
  ushort_t* Wqb  = srcb + SRC_E;
  ushort_t* Wkb  = Wqb + W_E;
  ushort_t* Wvb  = Wkb + W_E;
  ushort_t* Wob  = Wvb + W_E;
  ushort_t* Qb   = Wob + W_E;
  ushort_t* Kb   = Qb + QKV_E;
  ushort_t* Vtb  = Kb + QKV_E;    // V transposed: [b,h,kd,s]
  ushort_t* Obb  = Vtb + QKV_E;
  ushort_t* biaspre = Obb + QKV_E;                 // 8*136*128*32 ushorts
  float* numb  = (float*)(biaspre + (size_t)NHEAD * 136 * 128 * 32);
  float* rdenb = numb + NHEAD * S_LEN;
  float* gtabb = rdenb + NHEAD * S_LEN;

  // 1) bf16 convert + FIRE tables (independent, merged)
  hipLaunchKernelGGL(prep, dim3(7176), dim3(256), 0, stream,
                     src, Wq, Wk, Wv, Wo, srcb, Wqb, Wkb, Wvb, Wob,
                     c_raw, Lp, w1, b1, W2, b2, w3, b3, numb, rdenb, gtabb);
  // 2) QKV GEMM (768 blocks) + bias-pre (544 blocks), merged
  hipLaunchKernelGGL(gemm_bias, dim3(1312), dim3(256), 0, stream,
                     srcb, Wqb, Wkb, Wvb, (void*)Qb, (void*)Kb, (void*)Vtb,
                     1, 768, numb, rdenb, gtabb, biaspre);
  // 3) attention
  hipLaunchKernelGGL(fire_attn_mfma, dim3(1024), dim3(128), 0, stream,
                     Qb, Kb, Vtb, biaspre, Obb);
  // 4) output projection (f32 out)
  hipLaunchKernelGGL(gemm_bias, dim3(256), dim3(256), 0, stream,
                     Obb, Wob, Wob, Wob, (void*)outp, (void*)outp, (void*)outp,
                     0, 256, numb, rdenb, gtabb, biaspre);
}

// Round 8
// 166.376 us; speedup vs baseline: 1.5468x; 1.5468x over previous
//
#include <hip/hip_runtime.h>
#include <math.h>

#define S_LEN 1024
#define NHEAD 8
#define BATCH 8
#define KDIM  64
#define HID   32
#define NT    2048
#define TRI(q) ((q) * ((q) + 1) / 2)
// key-order bit-shuffle: m=[nb1 nb0 q1 q0 r1 r0] -> key=[nb1 q1 q0 nb0 r1 r0]
#define PERM(m) (((m) & 0x20) | (((m) & 0x0C) << 1) | (((m) & 0x10) >> 2) | ((m) & 3))
// LDS column swizzle key per row (3 bits, conflict-free for K(perm) and V reads)
#define SWZ(row) (((((row) >> 3) & 1) << 2) | ((row) & 3))

typedef __attribute__((ext_vector_type(8))) short bf16x8;
typedef __attribute__((ext_vector_type(4))) float f32x4;
typedef unsigned short ushort_t;

__device__ inline ushort_t f2bf(float f) {
  union { float f; unsigned u; } v; v.f = f;
  unsigned u = v.u;
  return (ushort_t)((u + 0x7FFFu + ((u >> 16) & 1u)) >> 16);
}
__device__ inline float bf2f(ushort_t u) {
  union { unsigned x; float f; } v; v.x = ((unsigned)u) << 16; return v.f;
}

// async global->LDS 16B: lane's LDS dest = lds_base + lane*16 (wave-uniform base)
__device__ inline void gl_lds16(const ushort_t* g, ushort_t* l) {
  __builtin_amdgcn_global_load_lds(
      (const __attribute__((address_space(1))) unsigned int*)g,
      (__attribute__((address_space(3))) unsigned int*)l, 16, 0, 0);
}

// ---------------------------------------------------------------------------
// Kernel 1: prep = to_bf16 (blocks 0..5119) + fire_tables (blocks 5120..7175).
// ---------------------------------------------------------------------------
__global__ __launch_bounds__(256) void prep(
    const float* __restrict__ s, const float* __restrict__ wq,
    const float* __restrict__ wk, const float* __restrict__ wv,
    const float* __restrict__ wo,
    ushort_t* __restrict__ sb, ushort_t* __restrict__ wqb,
    ushort_t* __restrict__ wkb, ushort_t* __restrict__ wvb,
    ushort_t* __restrict__ wob,
    const float* __restrict__ c_raw, const float* __restrict__ Lp,
    const float* __restrict__ w1, const float* __restrict__ b1,
    const float* __restrict__ W2, const float* __restrict__ b2,
    const float* __restrict__ w3, const float* __restrict__ b3,
    float* __restrict__ num_g, float* __restrict__ rden_g,
    float* __restrict__ gtab_g) {
  __shared__ float h1s[8][33];
  const int bx = blockIdx.x;
  const int tid = threadIdx.x;
  if (bx < 5120) {
    const float* src; ushort_t* dst; int base; float scale = 1.0f;
    if (bx < 4096)      { src = s;  dst = sb;  base = bx; }
    else if (bx < 4352) { src = wq; dst = wqb; base = bx - 4096; scale = 0.125f; }
    else if (bx < 4608) { src = wk; dst = wkb; base = bx - 4352; }
    else if (bx < 4864) { src = wv; dst = wvb; base = bx - 4608; }
    else                { src = wo; dst = wob; base = bx - 4864; }
    const int i = (base * 256 + tid) * 4;
    float4 v = *(const float4*)&src[i];
    ushort4 o;
    o.x = f2bf(v.x * scale); o.y = f2bf(v.y * scale);
    o.z = f2bf(v.z * scale); o.w = f2bf(v.w * scale);
    *(ushort4*)&dst[i] = o;
  } else {
    const int idx = bx - 5120;
    const int h = idx / 257;
    const int xb = idx % 257;
    const float cr = c_raw[h];
    const float c = (cr > 20.f) ? cr : log1pf(expf(cr));
    const int gid = xb * 256 + tid;
    if (gid < S_LEN) {
      num_g[h * S_LEN + gid] = log1pf(c * (float)gid);
      rden_g[h * S_LEN + gid] = 1.0f / log1pf(c * fmaxf(Lp[h], (float)(gid + 1)));
    }
    const int pl = tid >> 5;             // point-local 0..7
    const int j = tid & 31;              // hidden dim
    const int pt = xb * 8 + pl;
    const float x = (float)pt * (1.0f / NT);
    float v = x * w1[h * HID + j] + b1[h * HID + j];
    h1s[pl][j] = 0.5f * v * (1.0f + erff(v * 0.70710678118f));
    __syncthreads();
    float sm = b2[h * HID + j];
    const float* w2r = W2 + ((size_t)(h * HID + j)) * HID;
    #pragma unroll
    for (int k = 0; k < HID; ++k) sm += w2r[k] * h1s[pl][k];
    float g = 0.5f * sm * (1.0f + erff(sm * 0.70710678118f));
    float y = w3[h * HID + j] * g;
    #pragma unroll
    for (int off = 1; off < 32; off <<= 1) y += __shfl_xor(y, off);
    if (j == 0 && pt <= NT) gtab_g[h * (NT + 1) + pt] = y + b3[h];
  }
}

// ---------------------------------------------------------------------------
// GEMM tile body: C = A(Mx512 bf16) * W^T (512x512 bf16, NxK). 64x64 tile,
// 4 waves (wave w = rows w*16..w*16+16 x all 64 cols), BK=64,
// global_load_lds staging into XOR-swizzled LDS (slot = chunk ^ (row&7)).
// Small tile -> 16 KB LDS, ~16 acc VGPRs: many resident blocks/CU so the
// per-iteration barrier drains overlap ACROSS blocks (round-7's in-block
// register pipeline spilled to scratch; reverted).
// mode 0: f32 row-major Mx512. mode 1: bf16 scatter [b,h,s,kd].
// mode 2: V^T bf16 [b,h,kd,s] via LDS transpose.
// ---------------------------------------------------------------------------
__device__ __forceinline__ void gemm_tile(
    ushort_t* sAB, const ushort_t* __restrict__ A, const ushort_t* __restrict__ Wp,
    void* __restrict__ outp, int mode, int m0, int n0, int tid) {
  ushort_t* sA = sAB;            // 64x64
  ushort_t* sB = sAB + 4096;
  const int lane = tid & 63, w = tid >> 6, quad = lane >> 4, l16 = lane & 15;
  f32x4 acc[4];
  #pragma unroll
  for (int nb = 0; nb < 4; ++nb) acc[nb] = (f32x4)0.0f;

  const int r8 = lane >> 3;          // row within 8-row staging group
  const int gc = (lane & 7) ^ r8;    // swizzled source chunk for this lane
  const int sw = l16 & 7;            // frag-read swizzle key

  for (int kt = 0; kt < 512; kt += 64) {
    __syncthreads();
    #pragma unroll
    for (int j = 0; j < 2; ++j) {
      const int row = w * 16 + j * 8 + r8;
      gl_lds16(&A[(size_t)(m0 + row) * 512 + kt + gc * 8], &sA[(w * 16 + j * 8) * 64]);
      gl_lds16(&Wp[(size_t)(n0 + row) * 512 + kt + gc * 8], &sB[(w * 16 + j * 8) * 64]);
    }
    __syncthreads();
    #pragma unroll
    for (int ks = 0; ks < 2; ++ks) {
      const int off = ((ks * 4 + quad) ^ sw) * 8;
      bf16x8 af = *(bf16x8*)&sA[(w * 16 + l16) * 64 + off];
      #pragma unroll
      for (int nb = 0; nb < 4; ++nb) {
        bf16x8 bfr = *(bf16x8*)&sB[(nb * 16 + l16) * 64 + off];
        acc[nb] = __builtin_amdgcn_mfma_f32_16x16x32_bf16(af, bfr, acc[nb], 0, 0, 0);
      }
    }
  }

  if (mode == 2) {
    // V^T: acc -> LDS (XOR-swizzled [n][m]) -> coalesced [b,h,kd,s] stores
    __syncthreads();
    #pragma unroll
    for (int nb = 0; nb < 4; ++nb)
      #pragma unroll
      for (int r = 0; r < 4; ++r) {
        int nl = nb * 16 + l16;
        int ml = w * 16 + quad * 4 + r;
        sAB[nl * 64 + (((ml >> 3) ^ (nl & 7)) * 8) + (ml & 7)] = f2bf(acc[nb][r]);
      }
    __syncthreads();
    const int nl = tid >> 2, seg = tid & 3;
    const int ng = n0 + nl, hh = ng >> 6, kd = ng & 63;
    const int bb = m0 >> 10, sbase = m0 & 1023;
    ushort_t* vout = (ushort_t*)outp + (((size_t)(bb * NHEAD + hh)) * KDIM + kd) * S_LEN;
    #pragma unroll
    for (int c2 = 0; c2 < 2; ++c2) {
      int mc = seg * 2 + c2;
      bf16x8 vr = *(bf16x8*)&sAB[nl * 64 + ((mc ^ (nl & 7)) * 8)];
      *(bf16x8*)&vout[sbase + mc * 8] = vr;
    }
    return;
  }
  #pragma unroll
  for (int nb = 0; nb < 4; ++nb) {
    #pragma unroll
    for (int r = 0; r < 4; ++r) {
      int m = m0 + w * 16 + quad * 4 + r;
      int n = n0 + nb * 16 + l16;
      float v = acc[nb][r];
      if (mode == 1) {
        int bb = m >> 10, ss = m & 1023, hh = n >> 6, kd = n & 63;
        ((ushort_t*)outp)[(((size_t)(bb * NHEAD + hh)) * S_LEN + ss) * KDIM + kd] = f2bf(v);
      } else {
        ((float*)outp)[(size_t)m * 512 + n] = v;
      }
    }
  }
}

// ---------------------------------------------------------------------------
// Kernel 2/4: gemm_bias. Blocks < nGemm: 64x64 GEMM tiles. scatter=1 (QKV):
// z = idx%3 fastest so the 3 blocks sharing an A-strip are dispatch-adjacent
// (L2 locality); tile = idx/3, m0=(tile&127)*64, n0=(tile>>7)*64.
// scatter=0 (out-proj): z=0, m0=(idx&127)*64, n0=(idx>>7)*64.
// Blocks >= nGemm: bias-pre (2 tiles per 256-thr block) in PERM fragment
// order with causal -inf baked in.
// ---------------------------------------------------------------------------
__global__ __launch_bounds__(256) void gemm_bias(
    const ushort_t* __restrict__ A,
    const ushort_t* __restrict__ W0, const ushort_t* __restrict__ W1,
    const ushort_t* __restrict__ W2w,
    void* __restrict__ out0, void* __restrict__ out1, void* __restrict__ out2,
    int scatter, int nGemm,
    const float* __restrict__ num_g, const float* __restrict__ rden_g,
    const float* __restrict__ gtab_g, ushort_t* __restrict__ biaspre) {
  __shared__ __align__(16) ushort_t sAB[8192];   // 16 KB
  const int tid = threadIdx.x;
  if ((int)blockIdx.x < nGemm) {
    int z, tile;
    if (scatter) { z = blockIdx.x % 3; tile = blockIdx.x / 3; }
    else         { z = 0;              tile = blockIdx.x; }
    const int m0 = (tile & 127) * 64;
    const int n0 = (tile >> 7) * 64;
    const ushort_t* Wp = (z == 0) ? W0 : (z == 1) ? W1 : W2w;
    void* outp = (z == 0) ? out0 : (z == 1) ? out1 : out2;
    const int mode = scatter ? ((z == 2) ? 2 : 1) : 0;
    gemm_tile(sAB, A, Wp, outp, mode, m0, n0, tid);
  } else {
    const int idx = blockIdx.x - nGemm;      // 0..543
    const int h = idx / 68;
    const int pair = idx % 68;
    float* gtab_s = (float*)sAB;             // 2049 floats
    float* num_s = gtab_s + 2052;            // 1024 floats
    float* rden_s = num_s + 1024;            // [2][64]  (total ~12.9 KB < 16 KB)
    for (int i = tid; i <= NT; i += 256) gtab_s[i] = gtab_g[h * (NT + 1) + i];
    for (int i = tid; i < S_LEN; i += 256) num_s[i] = num_g[h * S_LEN + i];
    const int sub = tid >> 7, tid2 = tid & 127;
    const int tileIdx = pair * 2 + sub;
    int qt = 0;
    while (TRI(qt + 1) <= tileIdx) ++qt;
    const int t = tileIdx - TRI(qt);
    if (tid2 < 64) rden_s[sub * 64 + tid2] = rden_g[h * S_LEN + qt * 64 + tid2];
    __syncthreads();
    const int w = tid2 >> 6, lane = tid2 & 63, quad = lane >> 4, l16 = lane & 15;
    ushort_t vals[32];
    #pragma unroll
    for (int qg = 0; qg < 2; ++qg) {
      const int iloc = w * 32 + qg * 16 + l16;
      const int i = qt * 64 + iloc;
      const float rden = rden_s[sub * 64 + iloc];
      #pragma unroll
      for (int nb = 0; nb < 4; ++nb)
        #pragma unroll
        for (int r = 0; r < 4; ++r) {
          const int m = nb * 16 + quad * 4 + r;
          const int j = t * 64 + PERM(m);
          ushort_t out;
          if (j > i) {
            out = 0xFF80;  // bf16 -inf (causal)
          } else {
            const int d = i - j;
            float x = num_s[d] * rden;       // in [0,1)
            float tf = x * (float)NT;
            int it = (int)tf; it = it < (NT - 1) ? it : (NT - 1);
            float fr = tf - (float)it;
            float ga = gtab_s[it];
            out = f2bf(ga + (gtab_s[it + 1] - ga) * fr);
          }
          vals[qg * 16 + nb * 4 + r] = out;
        }
    }
    ushort_t* dst = &biaspre[((size_t)(h * 136 + tileIdx) * 128 + tid2) * 32];
    uint4 u[2];
    #pragma unroll
    for (int half = 0; half < 2; ++half) {
      #pragma unroll
      for (int v = 0; v < 8; ++v) ((ushort_t*)&u[0])[v] = vals[half * 16 + v];
      #pragma unroll
      for (int v = 0; v < 8; ++v) ((ushort_t*)&u[1])[v] = vals[half * 16 + 8 + v];
      *(uint4*)(dst + half * 16) = u[0];
      *(uint4*)(dst + half * 16 + 8) = u[1];
    }
  }
}

// ---------------------------------------------------------------------------
// Kernel 3: transposed MFMA causal flash attention (round-6 config, 171 µs).
// 1024 blocks x 128 thr (2 waves x 32 q-rows), one (qt, b, h) each; per-CU
// iteration count exactly 34 under round-robin. S^T = K.Q^T with PERM'd key
// order; P^T fragments for O^T = V^T.P^T register-local. K/V staged via
// global_load_lds with source-side XOR swizzle.
// ---------------------------------------------------------------------------
__global__ __launch_bounds__(128) void fire_attn_mfma(
    const ushort_t* __restrict__ Qg, const ushort_t* __restrict__ Kg,
    const ushort_t* __restrict__ Vtg, const ushort_t* __restrict__ biaspre,
    ushort_t* __restrict__ Ob) {
  __shared__ __align__(16) ushort_t Ks[64 * 64];
  __shared__ __align__(16) ushort_t Vt[64 * 64];
  const int tid = threadIdx.x;
  const int lane = tid & 63, w = tid >> 6, quad = lane >> 4, l16 = lane & 15;
  const int g = blockIdx.x >> 6;
  const int qt = (g < 8) ? (15 - g) : (g - 8);
  const int bh = blockIdx.x & 63, h = bh & 7, b = bh >> 3;

  // Q fragments (B-operand layout == A layout: [l16][quad*8+j]); Q pre-scaled 1/8
  bf16x8 q[2][2];
  {
    const size_t qb = (size_t)bh * S_LEN + qt * 64 + w * 32;
    #pragma unroll
    for (int qg = 0; qg < 2; ++qg)
      #pragma unroll
      for (int ks = 0; ks < 2; ++ks)
        q[qg][ks] = *(const bf16x8*)&Qg[(qb + qg * 16 + l16) * KDIM + ks * 32 + quad * 8];
  }

  const size_t kb = (size_t)bh * S_LEN * KDIM;
  const ushort_t* bptr = &biaspre[((size_t)(h * 136 + TRI(qt)) * 128 + tid) * 32];
  const int srow8 = lane >> 3;   // staging row-within-group
  const int sc = lane & 7;       // staging chunk

  f32x4 o[2][4];
  float ll[2] = {0.f, 0.f};
  #pragma unroll
  for (int qg = 0; qg < 2; ++qg)
    #pragma unroll
    for (int nb = 0; nb < 4; ++nb) o[qg][nb] = (f32x4)0.0f;

  for (int t = 0; t <= qt; ++t) {
    __syncthreads();
    #pragma unroll
    for (int j = 0; j < 4; ++j) {
      const int row = (w * 4 + j) * 8 + srow8;
      const int cc = sc ^ SWZ(row);
      gl_lds16(&Kg[kb + (size_t)(t * 64 + row) * 64 + cc * 8], &Ks[(w * 4 + j) * 512]);
      gl_lds16(&Vtg[kb + (size_t)row * 1024 + t * 64 + cc * 8], &Vt[(w * 4 + j) * 512]);
    }
    __syncthreads();

    // bias (fragment order, -inf baked); in flight during QK
    uint4 bb0 = ((const uint4*)(bptr + (size_t)t * 4096))[0];
    uint4 bb1 = ((const uint4*)(bptr + (size_t)t * 4096))[1];
    uint4 bb2 = ((const uint4*)(bptr + (size_t)t * 4096))[2];
    uint4 bb3 = ((const uint4*)(bptr + (size_t)t * 4096))[3];

    // ---- S^T = K . Q^T  (keys in PERM order on the m-dim)
    f32x4 s[2][4];
    #pragma unroll
    for (int qg = 0; qg < 2; ++qg)
      #pragma unroll
      for (int nb = 0; nb < 4; ++nb) s[qg][nb] = (f32x4)0.0f;
    #pragma unroll
    for (int ks = 0; ks < 2; ++ks) {
      #pragma unroll
      for (int nb = 0; nb < 4; ++nb) {
        const int rk = PERM(nb * 16 + l16);
        bf16x8 ak = *(bf16x8*)&Ks[rk * 64 + (((ks * 4 + quad) ^ SWZ(rk)) * 8)];
        #pragma unroll
        for (int qg = 0; qg < 2; ++qg)
          s[qg][nb] = __builtin_amdgcn_mfma_f32_16x16x32_bf16(ak, q[qg][ks], s[qg][nb], 0, 0, 0);
      }
    }

    // ---- P = exp(S + bias); no-max softmax (|logit| small); l per-lane
    ushort_t eb[2][16];
    #pragma unroll
    for (int qg = 0; qg < 2; ++qg) {
      #pragma unroll
      for (int nb = 0; nb < 4; ++nb)
        #pragma unroll
        for (int r = 0; r < 4; ++r) {
          const int v = qg * 16 + nb * 4 + r;
          const uint4& bq = (v < 8) ? bb0 : (v < 16) ? bb1 : (v < 24) ? bb2 : bb3;
          ushort_t bu = ((const ushort_t*)&bq)[v & 7];
          float p = __expf(s[qg][nb][r] + bf2f(bu));
          ll[qg] += p;
          eb[qg][nb * 4 + r] = f2bf(p);
        }
    }

    // ---- O^T += V^T . P^T   (P^T B-frags are register-local thanks to PERM)
    #pragma unroll
    for (int ks = 0; ks < 2; ++ks) {
      bf16x8 pf[2];
      #pragma unroll
      for (int qg = 0; qg < 2; ++qg) {
        union { bf16x8 v; unsigned u[4]; } pkx;
        pkx.u[0] = (unsigned)eb[qg][(2 * ks) * 4 + 0] | ((unsigned)eb[qg][(2 * ks) * 4 + 1] << 16);
        pkx.u[1] = (unsigned)eb[qg][(2 * ks) * 4 + 2] | ((unsigned)eb[qg][(2 * ks) * 4 + 3] << 16);
        pkx.u[2] = (unsigned)eb[qg][(2 * ks + 1) * 4 + 0] | ((unsigned)eb[qg][(2 * ks + 1) * 4 + 1] << 16);
        pkx.u[3] = (unsigned)eb[qg][(2 * ks + 1) * 4 + 2] | ((unsigned)eb[qg][(2 * ks + 1) * 4 + 3] << 16);
        pf[qg] = pkx.v;
      }
      #pragma unroll
      for (int nb = 0; nb < 4; ++nb) {
        const int rv = nb * 16 + l16;
        bf16x8 av = *(bf16x8*)&Vt[rv * 64 + (((ks * 4 + quad) ^ SWZ(rv)) * 8)];
        #pragma unroll
        for (int qg = 0; qg < 2; ++qg)
          o[qg][nb] = __builtin_amdgcn_mfma_f32_16x16x32_bf16(av, pf[qg], o[qg][nb], 0, 0, 0);
      }
    }
  }

  // ---- epilogue: l reduced across quads (qrow = qg*16+l16 for all lane vals)
  #pragma unroll
  for (int qg = 0; qg < 2; ++qg) {
    float rs = ll[qg];
    rs += __shfl_xor(rs, 16);
    rs += __shfl_xor(rs, 32);
    const float rl = 1.0f / rs;
    const size_t ob = ((size_t)(b * S_LEN + qt * 64 + w * 32 + qg * 16 + l16)) * 512 + h * KDIM;
    #pragma unroll
    for (int nb = 0; nb < 4; ++nb) {
      ushort4 ov;
      ov.x = f2bf(o[qg][nb][0] * rl);
      ov.y = f2bf(o[qg][nb][1] * rl);
      ov.z = f2bf(o[qg][nb][2] * rl);
      ov.w = f2bf(o[qg][nb][3] * rl);
      *(ushort4*)&Ob[ob + nb * 16 + quad * 4] = ov;
    }
  }
}

// ---------------------------------------------------------------------------
extern "C" void kernel_launch(void* const* d_in, const int* in_sizes, int n_in,
                              void* d_out, int out_size, void* d_ws, size_t ws_size,
                              hipStream_t stream) {
  const float* src   = (const float*)d_in[0];
  const float* Wq    = (const float*)d_in[1];
  const float* Wk    = (const float*)d_in[2];
  const float* Wv    = (const float*)d_in[3];
  const float* c_raw = (const float*)d_in[4];
  const float* Lp    = (const float*)d_in[5];
  const float* w1    = (const float*)d_in[6];
  const float* b1    = (const float*)d_in[7];
  const float* W2    = (const float*)d_in[8];
  const float* b2    = (const float*)d_in[9];
  const float* w3    = (const float*)d_in[10];
  const float* b3    = (const float*)d_in[11];
  const float* Wo    = (const float*)d_in[12];
  float* outp = (float*)d_out;

  const size_t SRC_E = 4194304;   // 8*1024*512
  const size_t W_E   = 262144;    // 512*512
  const size_t QKV_E = 4194304;   // 64*1024*64
  ushort_t* srcb = (ushort_t*)d_ws;
  ushort_t* Wqb  = srcb + SRC_E;
  ushort_t* Wkb  = Wqb + W_E;
  ushort_t* Wvb  = Wkb + W_E;
  ushort_t* Wob  = Wvb + W_E;
  ushort_t* Qb   = Wob + W_E;
  ushort_t* Kb   = Qb + QKV_E;
  ushort_t* Vtb  = Kb + QKV_E;    // V transposed: [b,h,kd,s]
  ushort_t* Obb  = Vtb + QKV_E;
  ushort_t* biaspre = Obb + QKV_E;                 // 8*136*128*32 ushorts
  float* numb  = (float*)(biaspre + (size_t)NHEAD * 136 * 128 * 32);
  float* rdenb = numb + NHEAD * S_LEN;
  float* gtabb = rdenb + NHEAD * S_LEN;

  // 1) bf16 convert + FIRE tables (independent, merged)
  hipLaunchKernelGGL(prep, dim3(7176), dim3(256), 0, stream,
                     src, Wq, Wk, Wv, Wo, srcb, Wqb, Wkb, Wvb, Wob,
                     c_raw, Lp, w1, b1, W2, b2, w3, b3, numb, rdenb, gtabb);
  // 2) QKV GEMM (3072 blocks, 64x64 tiles, z-fastest) + bias-pre (544 blocks)
  hipLaunchKernelGGL(gemm_bias, dim3(3616), dim3(256), 0, stream,
                     srcb, Wqb, Wkb, Wvb, (void*)Qb, (void*)Kb, (void*)Vtb,
                     1, 3072, numb, rdenb, gtabb, biaspre);
  // 3) attention
  hipLaunchKernelGGL(fire_attn_mfma, dim3(1024), dim3(128), 0, stream,
                     Qb, Kb, Vtb, biaspre, Obb);
  // 4) output projection (f32 out, 1024 blocks of 64x64)
  hipLaunchKernelGGL(gemm_bias, dim3(1024), dim3(256), 0, stream,
                     Obb, Wob, Wob, Wob, (void*)outp, (void*)outp, (void*)outp,
                     0, 1024, numb, rdenb, gtabb, biaspre);
}